// Round 3
// baseline (445.837 us; speedup 1.0000x reference)
//
#include <hip/hip_runtime.h>
#include <math.h>

// GaussianLayer: per row (B=524288): mu=x[0], sigma=exp(0.5*x[1]);
// pdf over xx=-99..99, cumsum over 199 bins. Output (B,199) fp32 = 417 MB.
//
// Write-bound (roofline ~66 us at the fill kernel's demonstrated 6.26 TB/s).
// R3: wave-per-row, zero LDS, zero barriers. Lane l computes bins 4l..4l+3
// with a local fma-cumsum; a 6-step __shfl_up inclusive scan of lane totals
// yields each lane's exclusive prefix; lanes 0..48 store one packed 16B
// group (796 B contiguous per row), lane 49 stores the 3-bin tail. Lanes
// >=50 (and lane 49's bin-199 term) only pollute prefixes of lanes that
// never store -> no compute masking needed. Each wave walks 32 consecutive
// rows (25 KB contiguous write streak per wave for L2 line merging).

#define NB       199
#define RPW      32      // rows per wave
#define NTHREADS 256

struct __attribute__((packed)) f4s { float a, b, c, d; };  // align-4 16B store

__global__ __launch_bounds__(NTHREADS, 8)
void gauss_cdf_kernel(const float2* __restrict__ x, float* __restrict__ out, int B) {
    const int lane   = threadIdx.x & 63;
    const int waveId = blockIdx.x * (NTHREADS / 64) + (threadIdx.x >> 6);
    const int r0     = waveId * RPW;
    const float binBase = (float)(4 * lane - 99);   // bin position of this lane's k=0

    #pragma unroll 1
    for (int i = 0; i < RPW; ++i) {
        int r = r0 + i;                 // wave-uniform
        if (r >= B) return;
        float2 v = x[r];                // same-address broadcast load
        float s        = __expf(-0.5f * v.y);        // 1/sigma
        float inv_norm = 0.3989422804014327f * s;    // 1/(sigma*sqrt(2pi))
        float coefA    = -0.5f * s * s;              // -1/(2 sigma^2)

        float tb = binBase - v.x;
        float t0 = tb, t1 = tb + 1.f, t2 = tb + 2.f, t3 = tb + 3.f;
        float e0 = __expf(coefA * t0 * t0);
        float e1 = __expf(coefA * t1 * t1);
        float e2 = __expf(coefA * t2 * t2);
        float e3 = __expf(coefA * t3 * t3);
        float c0 = inv_norm * e0;
        float c1 = fmaf(inv_norm, e1, c0);
        float c2 = fmaf(inv_norm, e2, c1);
        float c3 = fmaf(inv_norm, e3, c2);           // lane total

        // inclusive wave scan of lane totals
        float T = c3;
        #pragma unroll
        for (int off = 1; off < 64; off <<= 1) {
            float tt = __shfl_up(T, off, 64);
            if (lane >= off) T += tt;
        }
        float prefix = T - c3;                       // exclusive prefix

        float o0 = prefix + c0, o1 = prefix + c1, o2 = prefix + c2, o3 = prefix + c3;
        float* rowOut = out + (size_t)r * NB;
        if (lane < 49) {
            f4s val{o0, o1, o2, o3};
            *reinterpret_cast<f4s*>(rowOut + 4 * lane) = val;   // bins 4l..4l+3
        } else if (lane == 49) {
            rowOut[196] = o0; rowOut[197] = o1; rowOut[198] = o2;
        }
    }
}

extern "C" void kernel_launch(void* const* d_in, const int* in_sizes, int n_in,
                              void* d_out, int out_size, void* d_ws, size_t ws_size,
                              hipStream_t stream) {
    const float2* x = (const float2*)d_in[0];
    float* out = (float*)d_out;
    const int B = in_sizes[0] / 2;                          // (B,2) fp32
    const int waves  = (B + RPW - 1) / RPW;                 // 16384
    const int blocks = (waves + (NTHREADS / 64) - 1) / (NTHREADS / 64);  // 4096
    gauss_cdf_kernel<<<blocks, NTHREADS, 0, stream>>>(x, out, B);
}

// Round 4
// 418.052 us; speedup vs baseline: 1.0665x; 1.0665x over previous
//
#include <hip/hip_runtime.h>
#include <math.h>

// GaussianLayer: per row (B=524288): mu=x[0], sigma=exp(0.5*x[1]);
// pdf over xx=-99..99, cumsum over 199 bins. Output (B,199) fp32 = 417 MB.
// Write-bound; roofline ~67 us at the demonstrated 6.26 TB/s fill rate.
//
// R4: 32 rows/block (25.5 KB LDS -> 6 blocks/CU), 256 threads; thread
// (r=t&31, q=t>>5) computes segment q (25 bins) of row r into REGISTERS
// (eliminates R2's LDS read-modify-write fixup), publishes its segment
// total, then after one barrier adds the prefix of earlier segment totals
// and writes base-adjusted values to LDS once. Final phase: one fully
// contiguous 16B-aligned float4 sweep of the block's 32x199 region.
// No global store precedes any barrier -> no vmcnt(0) drain stalls.

#define ROWS 32
#define SEG  25     // bins per segment; 8 segments, last has 24
#define NB   199
#define NT   256

__global__ __launch_bounds__(NT, 6)
void gauss_cdf_kernel(const float2* __restrict__ x, float* __restrict__ out, int B) {
    __shared__ __align__(16) float lds[ROWS * NB];   // 25,472 B, flat == out layout
    __shared__ float tot[8 * ROWS];                  // per-segment totals [seg][row]

    const int tid = threadIdx.x;
    const int r   = tid & 31;        // row within block
    const int q   = tid >> 5;        // segment index 0..7
    const int rowBase = blockIdx.x * ROWS;
    const int row = rowBase + r;

    float mu = 0.f, coefA = 0.f, inv_norm = 0.f;
    if (row < B) {
        float2 v = x[row];
        mu = v.x;
        float s  = __expf(-0.5f * v.y);        // 1/sigma
        inv_norm = 0.3989422804014327f * s;    // 1/(sigma*sqrt(2pi))
        coefA    = -0.5f * s * s;              // -1/(2 sigma^2)
    }

    const int qs   = q * SEG;
    const int qlen = (q == 7) ? 24 : 25;       // bin 199 doesn't exist
    const float tb = (float)(qs - 99) - mu;

    // segment cumsum in registers (fully unrolled -> static indices)
    float c[SEG];
    float acc = 0.f;
    #pragma unroll
    for (int j = 0; j < SEG; ++j) {
        float t = tb + (float)j;
        acc += inv_norm * __expf(coefA * t * t);
        c[j] = acc;
    }
    tot[q * ROWS + r] = acc;   // q=7's extra bin harmless: tot[7] never read
    __syncthreads();

    // prefix of earlier segments' totals (<=7 LDS reads; q uniform per half-wave)
    float base = 0.f;
    #pragma unroll
    for (int k = 0; k < 7; ++k)
        if (k < q) base += tot[k * ROWS + r];

    float* dst = lds + r * NB + qs;
    #pragma unroll
    for (int j = 0; j < SEG; ++j)
        if (j < qlen) dst[j] = c[j] + base;
    __syncthreads();

    // contiguous float4 sweep: block region = 25,472 B at blockIdx*25,472 (16|)
    if (rowBase + ROWS <= B) {
        const float4* src = reinterpret_cast<const float4*>(lds);
        float4* d4 = reinterpret_cast<float4*>(out + (size_t)rowBase * NB);
        #pragma unroll 1
        for (int i = tid; i < (ROWS * NB) / 4; i += NT)
            d4[i] = src[i];
    } else {  // generic tail (unused for B=524288)
        for (int i = tid; i < ROWS * NB; i += NT) {
            int rr = i / NB;
            if (rowBase + rr < B) out[(size_t)rowBase * NB + i] = lds[i];
        }
    }
}

extern "C" void kernel_launch(void* const* d_in, const int* in_sizes, int n_in,
                              void* d_out, int out_size, void* d_ws, size_t ws_size,
                              hipStream_t stream) {
    const float2* x = (const float2*)d_in[0];
    float* out = (float*)d_out;
    const int B = in_sizes[0] / 2;                  // (B,2) fp32
    const int grid = (B + ROWS - 1) / ROWS;         // 16384 blocks
    gauss_cdf_kernel<<<grid, NT, 0, stream>>>(x, out, B);
}

// Round 6
// 411.225 us; speedup vs baseline: 1.0842x; 1.0166x over previous
//
#include <hip/hip_runtime.h>
#include <math.h>

// GaussianLayer: per row (B=524288): mu=x[0], sigma=exp(0.5*x[1]);
// pdf over xx=-99..99, cumsum over 199 bins. Output (B,199) fp32 = 417 MB.
// Write-bound; roofline ~67 us at the demonstrated 6.26 TB/s fill rate.
//
// R6 = R4 + NONTEMPORAL final stores (fixed: use clang ext_vector_type,
// HIP's float4 struct is rejected by the builtin). Theory: regular stores
// read-allocate in L2 (fetch-on-write-miss) -> true traffic 417+417 =
// 834 MB -> ~133 us, matching the ~150 us observed in R2/R4. Output is
// written once, never read: global_store_dwordx4 nt bypasses allocate.

#define ROWS 32
#define SEG  25     // bins per segment; 8 segments, last has 24
#define NB   199
#define NT   256

typedef float fx4 __attribute__((ext_vector_type(4)));  // native vec for nt builtin

__global__ __launch_bounds__(NT, 6)
void gauss_cdf_kernel(const float2* __restrict__ x, float* __restrict__ out, int B) {
    __shared__ __align__(16) float lds[ROWS * NB];   // 25,472 B, flat == out layout
    __shared__ float tot[8 * ROWS];                  // per-segment totals [seg][row]

    const int tid = threadIdx.x;
    const int r   = tid & 31;        // row within block
    const int q   = tid >> 5;        // segment index 0..7
    const int rowBase = blockIdx.x * ROWS;
    const int row = rowBase + r;

    float mu = 0.f, coefA = 0.f, inv_norm = 0.f;
    if (row < B) {
        float2 v = x[row];
        mu = v.x;
        float s  = __expf(-0.5f * v.y);        // 1/sigma
        inv_norm = 0.3989422804014327f * s;    // 1/(sigma*sqrt(2pi))
        coefA    = -0.5f * s * s;              // -1/(2 sigma^2)
    }

    const int qs   = q * SEG;
    const int qlen = (q == 7) ? 24 : 25;       // bin 199 doesn't exist
    const float tb = (float)(qs - 99) - mu;

    // segment cumsum in registers (fully unrolled -> static indices)
    float c[SEG];
    float acc = 0.f;
    #pragma unroll
    for (int j = 0; j < SEG; ++j) {
        float t = tb + (float)j;
        acc += inv_norm * __expf(coefA * t * t);
        c[j] = acc;
    }
    tot[q * ROWS + r] = acc;   // q=7's extra bin harmless: tot[7] never read
    __syncthreads();

    // prefix of earlier segments' totals (<=7 LDS reads)
    float base = 0.f;
    #pragma unroll
    for (int k = 0; k < 7; ++k)
        if (k < q) base += tot[k * ROWS + r];

    float* dst = lds + r * NB + qs;
    #pragma unroll
    for (int j = 0; j < SEG; ++j)
        if (j < qlen) dst[j] = c[j] + base;
    __syncthreads();

    // contiguous NONTEMPORAL float4 sweep: block region = 25,472 B,
    // offset blockIdx*25,472 (16B aligned, whole 64B lines per block)
    if (rowBase + ROWS <= B) {
        const fx4* src = reinterpret_cast<const fx4*>(lds);
        fx4* d4 = reinterpret_cast<fx4*>(out + (size_t)rowBase * NB);
        #pragma unroll 2
        for (int i = tid; i < (ROWS * NB) / 4; i += NT)
            __builtin_nontemporal_store(src[i], &d4[i]);
    } else {  // generic tail (unused for B=524288)
        for (int i = tid; i < ROWS * NB; i += NT) {
            int rr = i / NB;
            if (rowBase + rr < B)
                __builtin_nontemporal_store(lds[i], &out[(size_t)rowBase * NB + i]);
        }
    }
}

extern "C" void kernel_launch(void* const* d_in, const int* in_sizes, int n_in,
                              void* d_out, int out_size, void* d_ws, size_t ws_size,
                              hipStream_t stream) {
    const float2* x = (const float2*)d_in[0];
    float* out = (float*)d_out;
    const int B = in_sizes[0] / 2;                  // (B,2) fp32
    const int grid = (B + ROWS - 1) / ROWS;         // 16384 blocks
    gauss_cdf_kernel<<<grid, NT, 0, stream>>>(x, out, B);
}